// Round 13
// baseline (810.354 us; speedup 1.0000x reference)
//
#include <hip/hip_runtime.h>
#include <stdint.h>

typedef unsigned short v2u   __attribute__((ext_vector_type(2)));
typedef unsigned short u16x8 __attribute__((ext_vector_type(8)));
typedef short          s16x8 __attribute__((ext_vector_type(8)));
typedef float          f32x4 __attribute__((ext_vector_type(4)));

#define TM 64
#define TN 64

__device__ __forceinline__ uint32_t rnd_bf16(float f) {
    uint32_t u = __builtin_bit_cast(uint32_t, f);
    return (u + 0x7FFFu + ((u >> 16) & 1u)) >> 16;   // RNE f32 -> bf16 (finite)
}
__device__ __forceinline__ float bf16_to_f32(uint32_t bits16) {
    return __builtin_bit_cast(float, bits16 << 16);
}

// HW-validated pack transforms (r12/r15): mag floored at 0x2000;
// X side folds (sign - 0x3F80), W side keeps sign|mag.
__device__ __forceinline__ uint32_t pack_x(uint32_t w0, uint32_t w1) {
    uint32_t u = (w0 >> 16) | (w1 & 0xFFFF0000u);
    const v2u vfloor = {0x2000, 0x2000};
    v2u m = __builtin_bit_cast(v2u, u & 0x7FFF7FFFu);
    m = __builtin_elementwise_max(m, vfloor);
    uint32_t c = (u & 0x80008000u) ^ 0xC080C080u;    // sign - 0x3F80
    v2u xp = m + __builtin_bit_cast(v2u, c);
    return __builtin_bit_cast(uint32_t, xp);
}
__device__ __forceinline__ uint32_t pack_w(uint32_t w0, uint32_t w1) {
    uint32_t v = (w0 >> 16) | (w1 & 0xFFFF0000u);
    const v2u vfloor = {0x2000, 0x2000};
    v2u m = __builtin_bit_cast(v2u, v & 0x7FFF7FFFu);
    m = __builtin_elementwise_max(m, vfloor);
    return __builtin_bit_cast(uint32_t, m) | (v & 0x80008000u);
}

// Pre-pack pass: 4 raw f32-bit words -> 2 packed u32 (grid-stride, BW-bound).
__global__ void pack_kernel(const uint32_t* __restrict__ in,
                            uint32_t* __restrict__ out, int n4, int mode)
{
    int i = blockIdx.x * blockDim.x + threadIdx.x;
    const int stride = gridDim.x * blockDim.x;
    for (; i < n4; i += stride) {
        uint4 v = ((const uint4*)in)[i];
        uint2 o;
        if (mode == 0) { o.x = pack_x(v.x, v.y); o.y = pack_x(v.z, v.w); }
        else           { o.x = pack_w(v.x, v.y); o.y = pack_w(v.z, v.w); }
        ((uint2*)out)[i] = o;
    }
}

// ROUND 25. r24 (explicit reg pipeline, bounds(256,2)): NULL — compiler
// folded it back (VGPR 84 unchanged). Issue accounting per SIMD per chunk
// (wall ~11.2k cyc @ 2.5 waves/SIMD): matrix 55%, VALU 23%, LDS ~18%,
// issue-port 28% -> NOTHING saturated = latency-bound. Occupancy has never
// been probed with the DMA structure (r17's null was in-loop-pack era;
// r23/r24 both ran ~2.5-3 blocks/CU). This round: force 4 blocks/CU via
// __launch_bounds__(256,4) (128 unified regs: acc 64 AGPR + xf 32 + wf 16
// + bt 16 + addr ~8; LDS 4x32=128<=160 KiB). Inner loop = r23 (validated).
// Spill tripwire: WRITE_SIZE > 40MB. If occupancy up & dur flat ->
// latency model dead -> dot2-hybrid next.
__global__ __launch_bounds__(256, 4)
void fpma_gemm_pre(const uint32_t* __restrict__ Xq,  // packed [M,K/2]
                   const uint32_t* __restrict__ Wq,  // packed [N,K/2]
                   const float*    __restrict__ Bias,// [N] f32 (bf16-exact)
                   float* __restrict__ Out,          // [M,N] f32 (bf16-valued)
                   int M, int N, int K)
{
    __shared__ uint32_t Xp[2][2][64 * 16];  // [buf][ksub][row*16], oct-swizzled
    __shared__ uint32_t Wp[2][2][64 * 16];

    const int tid  = threadIdx.x;
    const int lane = tid & 63;
    const int warp = tid >> 6;
    const int wm = warp >> 1, wn = warp & 1;
    const int m0 = blockIdx.y * TM;
    const int n0 = blockIdx.x * TN;

    // compute-side roles (r15/r16-validated A/D mapping)
    const int cc = lane & 15;
    const int q  = lane >> 4;            // k-octet within a 32-k sub-tile
    const int mi = cc >> 2;
    const int ni = cc & 3;

    const int xrd = (32 * wm + mi) * 16 + ((q ^ mi) << 2);
    int wrd[4];
    #pragma unroll
    for (int t = 0; t < 4; ++t)
        wrd[t] = (32 * wn + ni) * 16 + ((q ^ ni) << 2) + (((q + t) & 3) << 6);

    // B selectors: ones iff D col-group (cc>>2) == (q+t)&3
    u16x8 bt[4];
    #pragma unroll
    for (int t = 0; t < 4; ++t) {
        unsigned short v = ((cc >> 2) == ((q + t) & 3)) ? (unsigned short)0x3F80
                                                        : (unsigned short)0;
        bt[t] = (u16x8){v, v, v, v, v, v, v, v};
    }

    // staging roles: DMA dest linear tid*16B per sub-tile; swizzle moved to
    // the per-lane GLOBAL source octet (rule #21/m173; r22-validated).
    const int srow = tid >> 2;           // 0..63
    const int soct = tid & 3;            // 0..3
    const int Kp = K >> 1;               // packed words per row
    const int swz = (soct ^ (srow & 3)) << 2;
    const uint32_t* xsrc = Xq + (size_t)(m0 + srow) * Kp + swz;
    const uint32_t* wsrc = Wq + (size_t)(n0 + srow) * Kp + swz;

    f32x4 acc[8][2];
    #pragma unroll
    for (int a = 0; a < 8; ++a)
        #pragma unroll
        for (int bg = 0; bg < 2; ++bg) acc[a][bg] = (f32x4){0.f, 0.f, 0.f, 0.f};

    // prologue: DMA chunk 0 (both 32-k sub-tiles) into buf 0
    __builtin_amdgcn_global_load_lds(xsrc,      &Xp[0][0][tid << 2], 16, 0, 0);
    __builtin_amdgcn_global_load_lds(xsrc + 16, &Xp[0][1][tid << 2], 16, 0, 0);
    __builtin_amdgcn_global_load_lds(wsrc,      &Wp[0][0][tid << 2], 16, 0, 0);
    __builtin_amdgcn_global_load_lds(wsrc + 16, &Wp[0][1][tid << 2], 16, 0, 0);
    xsrc += 32; wsrc += 32;
    __syncthreads();   // drain: chunk-0 staging visible

    const int ksteps = K / 64;
    #pragma unroll 1
    for (int kt = 0; kt < ksteps; ++kt) {
        const int cur = kt & 1;
        if (kt + 1 < ksteps) {
            __builtin_amdgcn_global_load_lds(xsrc,      &Xp[cur ^ 1][0][tid << 2], 16, 0, 0);
            __builtin_amdgcn_global_load_lds(xsrc + 16, &Xp[cur ^ 1][1][tid << 2], 16, 0, 0);
            __builtin_amdgcn_global_load_lds(wsrc,      &Wp[cur ^ 1][0][tid << 2], 16, 0, 0);
            __builtin_amdgcn_global_load_lds(wsrc + 16, &Wp[cur ^ 1][1][tid << 2], 16, 0, 0);
            xsrc += 32; wsrc += 32;
        }

        __builtin_amdgcn_s_setprio(1);
        #pragma unroll
        for (int ks = 0; ks < 2; ++ks) {
            u16x8 xf[8];
            #pragma unroll
            for (int a = 0; a < 8; ++a)
                xf[a] = __builtin_bit_cast(u16x8,
                            *(const uint4*)&Xp[cur][ks][xrd + a * 64]);
            #pragma unroll
            for (int bg = 0; bg < 2; ++bg) {
                u16x8 wf[4];
                #pragma unroll
                for (int t = 0; t < 4; ++t)
                    wf[t] = __builtin_bit_cast(u16x8,
                                *(const uint4*)&Wp[cur][ks][wrd[t] + bg * 256]);
                #pragma unroll
                for (int t = 0; t < 4; ++t)
                    #pragma unroll
                    for (int a = 0; a < 8; ++a) {
                        u16x8 p = xf[a] + wf[t];       // 4x v_pk_add_u16
                        acc[a][bg] = __builtin_amdgcn_mfma_f32_16x16x32_bf16(
                            __builtin_bit_cast(s16x8, p),
                            __builtin_bit_cast(s16x8, bt[t]),
                            acc[a][bg], 0, 0, 0);
                    }
            }
        }
        __builtin_amdgcn_s_setprio(0);
        __syncthreads();   // drains DMA into cur^1 + lgkm; publishes
    }

    // Epilogue (r16-validated). acc[a][bg]: lane (cc,q), elem j =
    // out(m0+32wm+4a+q, n0+32wn+16bg+4*(cc>>2)+j); lane stores a's with
    // a&3 == cc&3 (disjoint, complete cover of 64x64 tile).
    const int g = cc >> 2;
    f32x4 bias_[2];
    #pragma unroll
    for (int bg = 0; bg < 2; ++bg)
        bias_[bg] = *(const f32x4*)&Bias[n0 + 32 * wn + 16 * bg + 4 * g];

    #pragma unroll
    for (int a = 0; a < 8; ++a) {
        if ((cc & 3) == (a & 3)) {
            #pragma unroll
            for (int bg = 0; bg < 2; ++bg) {
                float o[4];
                #pragma unroll
                for (int j = 0; j < 4; ++j)
                    o[j] = bf16_to_f32(rnd_bf16(
                               bf16_to_f32(rnd_bf16(acc[a][bg][j])) + bias_[bg][j]));
                const size_t row = (size_t)(m0 + 32 * wm + 4 * a + q) * N;
                *(float4*)&Out[row + n0 + 32 * wn + 16 * bg + 4 * g] =
                    make_float4(o[0], o[1], o[2], o[3]);
            }
        }
    }
}

// Fallback (ws too small): r16 path — in-kernel pack, BK=32, reg prefetch.
__global__ __launch_bounds__(256, 3)
void fpma_gemm_fb(const uint32_t* __restrict__ X, const uint32_t* __restrict__ Wt,
                  const float* __restrict__ Bias, float* __restrict__ Out,
                  int M, int N, int K)
{
    __shared__ uint32_t Xp[2][64 * 16];
    __shared__ uint32_t Wp[2][64 * 16];

    const int tid  = threadIdx.x;
    const int lane = tid & 63;
    const int warp = tid >> 6;
    const int wm = warp >> 1, wn = warp & 1;
    const int m0 = blockIdx.y * TM;
    const int n0 = blockIdx.x * TN;
    const int cc = lane & 15;
    const int q  = lane >> 4;
    const int mi = cc >> 2;
    const int ni = cc & 3;
    const int xrd = (32 * wm + mi) * 16 + ((q ^ mi) << 2);
    int wrd[4];
    #pragma unroll
    for (int t = 0; t < 4; ++t)
        wrd[t] = (32 * wn + ni) * 16 + ((q ^ ni) << 2) + (((q + t) & 3) << 6);
    u16x8 bt[4];
    #pragma unroll
    for (int t = 0; t < 4; ++t) {
        unsigned short v = ((cc >> 2) == ((q + t) & 3)) ? (unsigned short)0x3F80
                                                        : (unsigned short)0;
        bt[t] = (u16x8){v, v, v, v, v, v, v, v};
    }
    const int srow = tid >> 2;
    const int soct = tid & 3;
    const uint32_t* xptr = X  + (size_t)(m0 + srow) * K + soct * 8;
    const uint32_t* wptr = Wt + (size_t)(n0 + srow) * K + soct * 8;
    const int st = srow * 16 + ((soct ^ (srow & 3)) << 2);

    f32x4 acc[8][2];
    #pragma unroll
    for (int a = 0; a < 8; ++a)
        #pragma unroll
        for (int bg = 0; bg < 2; ++bg) acc[a][bg] = (f32x4){0.f, 0.f, 0.f, 0.f};

    {
        uint4 a0 = *(const uint4*)(xptr), a1 = *(const uint4*)(xptr + 4);
        uint4 b0 = *(const uint4*)(wptr), b1 = *(const uint4*)(wptr + 4);
        *(uint4*)&Xp[0][st] = (uint4){pack_x(a0.x,a0.y), pack_x(a0.z,a0.w),
                                      pack_x(a1.x,a1.y), pack_x(a1.z,a1.w)};
        *(uint4*)&Wp[0][st] = (uint4){pack_w(b0.x,b0.y), pack_w(b0.z,b0.w),
                                      pack_w(b1.x,b1.y), pack_w(b1.z,b1.w)};
    }
    uint4 gx0 = {0,0,0,0}, gx1 = {0,0,0,0}, gw0 = {0,0,0,0}, gw1 = {0,0,0,0};
    const int ksteps = K / 32;
    if (ksteps > 1) {
        xptr += 32; wptr += 32;
        gx0 = *(const uint4*)(xptr); gx1 = *(const uint4*)(xptr + 4);
        gw0 = *(const uint4*)(wptr); gw1 = *(const uint4*)(wptr + 4);
    }
    __syncthreads();

    #pragma unroll 1
    for (int kt = 0; kt < ksteps; ++kt) {
        const int cur = kt & 1;
        if (kt + 1 < ksteps) {
            *(uint4*)&Xp[cur ^ 1][st] = (uint4){pack_x(gx0.x,gx0.y), pack_x(gx0.z,gx0.w),
                                                pack_x(gx1.x,gx1.y), pack_x(gx1.z,gx1.w)};
            *(uint4*)&Wp[cur ^ 1][st] = (uint4){pack_w(gw0.x,gw0.y), pack_w(gw0.z,gw0.w),
                                                pack_w(gw1.x,gw1.y), pack_w(gw1.z,gw1.w)};
            if (kt + 2 < ksteps) {
                xptr += 32; wptr += 32;
                gx0 = *(const uint4*)(xptr); gx1 = *(const uint4*)(xptr + 4);
                gw0 = *(const uint4*)(wptr); gw1 = *(const uint4*)(wptr + 4);
            }
        }
        u16x8 xf[8];
        #pragma unroll
        for (int a = 0; a < 8; ++a)
            xf[a] = __builtin_bit_cast(u16x8, *(const uint4*)&Xp[cur][xrd + a * 64]);
        #pragma unroll
        for (int bg = 0; bg < 2; ++bg) {
            u16x8 wf[4];
            #pragma unroll
            for (int t = 0; t < 4; ++t)
                wf[t] = __builtin_bit_cast(u16x8, *(const uint4*)&Wp[cur][wrd[t] + bg * 256]);
            #pragma unroll
            for (int t = 0; t < 4; ++t)
                #pragma unroll
                for (int a = 0; a < 8; ++a) {
                    u16x8 p = xf[a] + wf[t];
                    acc[a][bg] = __builtin_amdgcn_mfma_f32_16x16x32_bf16(
                        __builtin_bit_cast(s16x8, p),
                        __builtin_bit_cast(s16x8, bt[t]), acc[a][bg], 0, 0, 0);
                }
        }
        __syncthreads();
    }

    const int g = cc >> 2;
    f32x4 bias_[2];
    #pragma unroll
    for (int bg = 0; bg < 2; ++bg)
        bias_[bg] = *(const f32x4*)&Bias[n0 + 32 * wn + 16 * bg + 4 * g];
    #pragma unroll
    for (int a = 0; a < 8; ++a) {
        if ((cc & 3) == (a & 3)) {
            #pragma unroll
            for (int bg = 0; bg < 2; ++bg) {
                float o[4];
                #pragma unroll
                for (int j = 0; j < 4; ++j)
                    o[j] = bf16_to_f32(rnd_bf16(
                               bf16_to_f32(rnd_bf16(acc[a][bg][j])) + bias_[bg][j]));
                const size_t row = (size_t)(m0 + 32 * wm + 4 * a + q) * N;
                *(float4*)&Out[row + n0 + 32 * wn + 16 * bg + 4 * g] =
                    make_float4(o[0], o[1], o[2], o[3]);
            }
        }
    }
}

extern "C" void kernel_launch(void* const* d_in, const int* in_sizes, int n_in,
                              void* d_out, int out_size, void* d_ws, size_t ws_size,
                              hipStream_t stream) {
    (void)n_in; (void)out_size;
    const uint32_t* X = (const uint32_t*)d_in[0];   // f32 words (bf16-exact)
    const uint32_t* W = (const uint32_t*)d_in[1];
    const float*    B = (const float*)d_in[2];
    float* O = (float*)d_out;                       // f32 out (bf16-valued)

    int N = in_sizes[2];                       // bias [1,N], elements
    int K = (N > 0) ? in_sizes[1] / N : 0;     // weight [N,K]
    int M = (K > 0) ? in_sizes[0] / K : 0;     // input [M,K]
    if (N <= 0 || K <= 0 || M <= 0 ||
        (long long)N * K != (long long)in_sizes[1] ||
        (long long)M * K != (long long)in_sizes[0] ||
        (M % TM) || (N % TN) || (K % 64)) {
        M = 4096; K = 2048; N = 2048;          // documented problem shape
    }

    const size_t xq_words = (size_t)M * (K / 2);
    const size_t wq_words = (size_t)N * (K / 2);
    const size_t need = (xq_words + wq_words) * 4;

    dim3 grid(N / TN, M / TM);
    if (d_ws != nullptr && ws_size >= need) {
        uint32_t* Xq = (uint32_t*)d_ws;
        uint32_t* Wq = Xq + xq_words;
        pack_kernel<<<1024, 256, 0, stream>>>(X, Xq, (int)(xq_words / 2), 0);
        pack_kernel<<<1024, 256, 0, stream>>>(W, Wq, (int)(wq_words / 2), 1);
        fpma_gemm_pre<<<grid, 256, 0, stream>>>(Xq, Wq, B, O, M, N, K);
    } else {
        fpma_gemm_fb<<<grid, 256, 0, stream>>>(X, W, B, O, M, N, K);
    }
}

// Round 14
// 539.644 us; speedup vs baseline: 1.5016x; 1.5016x over previous
//
#include <hip/hip_runtime.h>
#include <stdint.h>

typedef unsigned short v2u   __attribute__((ext_vector_type(2)));
typedef unsigned short u16x8 __attribute__((ext_vector_type(8)));
typedef short          s16x8 __attribute__((ext_vector_type(8)));
typedef float          f32x4 __attribute__((ext_vector_type(4)));

#define TM 64
#define TN 64

__device__ __forceinline__ uint32_t rnd_bf16(float f) {
    uint32_t u = __builtin_bit_cast(uint32_t, f);
    return (u + 0x7FFFu + ((u >> 16) & 1u)) >> 16;   // RNE f32 -> bf16 (finite)
}
__device__ __forceinline__ float bf16_to_f32(uint32_t bits16) {
    return __builtin_bit_cast(float, bits16 << 16);
}

// HW-validated pack transforms (r12/r15): mag floored at 0x2000;
// X side folds (sign - 0x3F80), W side keeps sign|mag.
__device__ __forceinline__ uint32_t pack_x(uint32_t w0, uint32_t w1) {
    uint32_t u = (w0 >> 16) | (w1 & 0xFFFF0000u);
    const v2u vfloor = {0x2000, 0x2000};
    v2u m = __builtin_bit_cast(v2u, u & 0x7FFF7FFFu);
    m = __builtin_elementwise_max(m, vfloor);
    uint32_t c = (u & 0x80008000u) ^ 0xC080C080u;    // sign - 0x3F80
    v2u xp = m + __builtin_bit_cast(v2u, c);
    return __builtin_bit_cast(uint32_t, xp);
}
__device__ __forceinline__ uint32_t pack_w(uint32_t w0, uint32_t w1) {
    uint32_t v = (w0 >> 16) | (w1 & 0xFFFF0000u);
    const v2u vfloor = {0x2000, 0x2000};
    v2u m = __builtin_bit_cast(v2u, v & 0x7FFF7FFFu);
    m = __builtin_elementwise_max(m, vfloor);
    return __builtin_bit_cast(uint32_t, m) | (v & 0x80008000u);
}

// Pre-pack pass: 4 raw f32-bit words -> 2 packed u32 (grid-stride, BW-bound).
__global__ void pack_kernel(const uint32_t* __restrict__ in,
                            uint32_t* __restrict__ out, int n4, int mode)
{
    int i = blockIdx.x * blockDim.x + threadIdx.x;
    const int stride = gridDim.x * blockDim.x;
    for (; i < n4; i += stride) {
        uint4 v = ((const uint4*)in)[i];
        uint2 o;
        if (mode == 0) { o.x = pack_x(v.x, v.y); o.y = pack_x(v.z, v.w); }
        else           { o.x = pack_w(v.x, v.y); o.y = pack_w(v.z, v.w); }
        ((uint2*)out)[i] = o;
    }
}

// ROUND 26. r25 (bounds(256,4)): SPILL — VGPR 64, WRITE 1.87GB, 810 us.
// Occupancy can't rise past ~3 blocks/CU without spilling; lever dead.
// Per discriminator: dot2-HYBRID on the r23 base (470 us, bounds(256,3)).
// Offload t=3 (1/4 of products) from MFMA to the r12-validated
// v_pk_add_u16 + v_dot2_f32_bf16 path, accumulating per-lane scalars
// S[a][bg]. Pipe totals: matrix 265->199 us, VALU 109pk+109dot2 ~= 220 —
// balanced; 16 independent dot2 chains/wave give the scheduler issueable
// VALU work inside every ds_read/MFMA latency gap (r12 sustained 84% duty).
// Octet audit: t=0..2 MFMA gives col-group g octets {g,g-1,g-2}; missing
// (g+1)&3 = exactly the octet lane (4q+j, (g+1)&3) holds in S. Epilogue:
// one barrier, publish S via Xp-as-scratch (per-warp 1KiB), 16 reads, add
// before bf16 round. Same product set, reassociated -> absmax ~0.016-0.03.
__global__ __launch_bounds__(256, 3)
void fpma_gemm_pre(const uint32_t* __restrict__ Xq,  // packed [M,K/2]
                   const uint32_t* __restrict__ Wq,  // packed [N,K/2]
                   const float*    __restrict__ Bias,// [N] f32 (bf16-exact)
                   float* __restrict__ Out,          // [M,N] f32 (bf16-valued)
                   int M, int N, int K)
{
    __shared__ uint32_t Xp[2][2][64 * 16];  // [buf][ksub][row*16], oct-swizzled
    __shared__ uint32_t Wp[2][2][64 * 16];

    const int tid  = threadIdx.x;
    const int lane = tid & 63;
    const int warp = tid >> 6;
    const int wm = warp >> 1, wn = warp & 1;
    const int m0 = blockIdx.y * TM;
    const int n0 = blockIdx.x * TN;

    // compute-side roles (r15/r16-validated A/D mapping)
    const int cc = lane & 15;
    const int q  = lane >> 4;            // k-octet within a 32-k sub-tile
    const int mi = cc >> 2;
    const int ni = cc & 3;

    const int xrd = (32 * wm + mi) * 16 + ((q ^ mi) << 2);
    int wrd[4];
    #pragma unroll
    for (int t = 0; t < 4; ++t)
        wrd[t] = (32 * wn + ni) * 16 + ((q ^ ni) << 2) + (((q + t) & 3) << 6);

    // B selectors for MFMA rotations t=0..2
    u16x8 bt[3];
    #pragma unroll
    for (int t = 0; t < 3; ++t) {
        unsigned short v = ((cc >> 2) == ((q + t) & 3)) ? (unsigned short)0x3F80
                                                        : (unsigned short)0;
        bt[t] = (u16x8){v, v, v, v, v, v, v, v};
    }
    const float ones_pair = __builtin_bit_cast(float, 0x3F803F80u); // {1,1} bf16

    // staging roles: DMA dest linear tid*16B per sub-tile; swizzle moved to
    // the per-lane GLOBAL source octet (rule #21/m173; r22-validated).
    const int srow = tid >> 2;           // 0..63
    const int soct = tid & 3;            // 0..3
    const int Kp = K >> 1;               // packed words per row
    const int swz = (soct ^ (srow & 3)) << 2;
    const uint32_t* xsrc = Xq + (size_t)(m0 + srow) * Kp + swz;
    const uint32_t* wsrc = Wq + (size_t)(n0 + srow) * Kp + swz;

    f32x4 acc[8][2];
    float S[8][2];                       // dot2 partials (t=3 octet)
    #pragma unroll
    for (int a = 0; a < 8; ++a)
        #pragma unroll
        for (int bg = 0; bg < 2; ++bg) {
            acc[a][bg] = (f32x4){0.f, 0.f, 0.f, 0.f};
            S[a][bg] = 0.f;
        }

    // prologue: DMA chunk 0 (both 32-k sub-tiles) into buf 0
    __builtin_amdgcn_global_load_lds(xsrc,      &Xp[0][0][tid << 2], 16, 0, 0);
    __builtin_amdgcn_global_load_lds(xsrc + 16, &Xp[0][1][tid << 2], 16, 0, 0);
    __builtin_amdgcn_global_load_lds(wsrc,      &Wp[0][0][tid << 2], 16, 0, 0);
    __builtin_amdgcn_global_load_lds(wsrc + 16, &Wp[0][1][tid << 2], 16, 0, 0);
    xsrc += 32; wsrc += 32;
    __syncthreads();   // drain: chunk-0 staging visible

    const int ksteps = K / 64;
    #pragma unroll 1
    for (int kt = 0; kt < ksteps; ++kt) {
        const int cur = kt & 1;
        if (kt + 1 < ksteps) {
            __builtin_amdgcn_global_load_lds(xsrc,      &Xp[cur ^ 1][0][tid << 2], 16, 0, 0);
            __builtin_amdgcn_global_load_lds(xsrc + 16, &Xp[cur ^ 1][1][tid << 2], 16, 0, 0);
            __builtin_amdgcn_global_load_lds(wsrc,      &Wp[cur ^ 1][0][tid << 2], 16, 0, 0);
            __builtin_amdgcn_global_load_lds(wsrc + 16, &Wp[cur ^ 1][1][tid << 2], 16, 0, 0);
            xsrc += 32; wsrc += 32;
        }

        __builtin_amdgcn_s_setprio(1);
        #pragma unroll
        for (int ks = 0; ks < 2; ++ks) {
            u16x8 xf[8];
            #pragma unroll
            for (int a = 0; a < 8; ++a)
                xf[a] = __builtin_bit_cast(u16x8,
                            *(const uint4*)&Xp[cur][ks][xrd + a * 64]);
            #pragma unroll
            for (int bg = 0; bg < 2; ++bg) {
                u16x8 wf[4];
                #pragma unroll
                for (int t = 0; t < 4; ++t)
                    wf[t] = __builtin_bit_cast(u16x8,
                                *(const uint4*)&Wp[cur][ks][wrd[t] + bg * 256]);
                // t = 0..2 via MFMA (96 MFMA/chunk)
                #pragma unroll
                for (int t = 0; t < 3; ++t)
                    #pragma unroll
                    for (int a = 0; a < 8; ++a) {
                        u16x8 p = xf[a] + wf[t];       // 4x v_pk_add_u16
                        acc[a][bg] = __builtin_amdgcn_mfma_f32_16x16x32_bf16(
                            __builtin_bit_cast(s16x8, p),
                            __builtin_bit_cast(s16x8, bt[t]),
                            acc[a][bg], 0, 0, 0);
                    }
                // t = 3 via dot2 on the VALU pipe (independent chains)
                #pragma unroll
                for (int a = 0; a < 8; ++a) {
                    u16x8 p = xf[a] + wf[3];           // 4x v_pk_add_u16
                    uint4 pb = __builtin_bit_cast(uint4, p);
                    asm("v_dot2_f32_bf16 %0, %1, %2, %0" : "+v"(S[a][bg])
                        : "v"(__builtin_bit_cast(float, pb.x)), "v"(ones_pair));
                    asm("v_dot2_f32_bf16 %0, %1, %2, %0" : "+v"(S[a][bg])
                        : "v"(__builtin_bit_cast(float, pb.y)), "v"(ones_pair));
                    asm("v_dot2_f32_bf16 %0, %1, %2, %0" : "+v"(S[a][bg])
                        : "v"(__builtin_bit_cast(float, pb.z)), "v"(ones_pair));
                    asm("v_dot2_f32_bf16 %0, %1, %2, %0" : "+v"(S[a][bg])
                        : "v"(__builtin_bit_cast(float, pb.w)), "v"(ones_pair));
                }
            }
        }
        __builtin_amdgcn_s_setprio(0);
        __syncthreads();   // drains DMA into cur^1 + lgkm; publishes
    }

    // ---- epilogue ----
    // Publish dot2 partials via Xp-as-scratch (all warps past compute first).
    __syncthreads();
    uint32_t* sb = &Xp[0][0][0] + (warp << 10);   // 1024 words per warp
    #pragma unroll
    for (int a = 0; a < 8; ++a)
        #pragma unroll
        for (int bg = 0; bg < 2; ++bg)
            sb[lane * 16 + a * 2 + bg] = __builtin_bit_cast(uint32_t, S[a][bg]);

    // Gather missing-octet partials: element (a,bg,j) at storer lane (cc,q)
    // lives at lane l' = ((g+1)&3)*16 + 4q + j, entry [a][bg]. a needed is
    // (cc&3)+4*ah -> dynamic LDS address (fine), static Sp index (rule #20).
    const int g = cc >> 2;
    const int ls = (((g + 1) & 3) << 4) + (q << 2);
    float Sp[2][2][4];
    #pragma unroll
    for (int ah = 0; ah < 2; ++ah)
        #pragma unroll
        for (int bg = 0; bg < 2; ++bg)
            #pragma unroll
            for (int j = 0; j < 4; ++j)
                Sp[ah][bg][j] = __builtin_bit_cast(float,
                    sb[(ls + j) * 16 + ((cc & 3) + 4 * ah) * 2 + bg]);

    f32x4 bias_[2];
    #pragma unroll
    for (int bg = 0; bg < 2; ++bg)
        bias_[bg] = *(const f32x4*)&Bias[n0 + 32 * wn + 16 * bg + 4 * g];

    #pragma unroll
    for (int a = 0; a < 8; ++a) {
        if ((cc & 3) == (a & 3)) {
            #pragma unroll
            for (int bg = 0; bg < 2; ++bg) {
                float o[4];
                #pragma unroll
                for (int j = 0; j < 4; ++j) {
                    float tot = acc[a][bg][j] + Sp[a >> 2][bg][j];
                    o[j] = bf16_to_f32(rnd_bf16(
                               bf16_to_f32(rnd_bf16(tot)) + bias_[bg][j]));
                }
                const size_t row = (size_t)(m0 + 32 * wm + 4 * a + q) * N;
                *(float4*)&Out[row + n0 + 32 * wn + 16 * bg + 4 * g] =
                    make_float4(o[0], o[1], o[2], o[3]);
            }
        }
    }
}

// Fallback (ws too small): r16 path — in-kernel pack, BK=32, reg prefetch.
__global__ __launch_bounds__(256, 3)
void fpma_gemm_fb(const uint32_t* __restrict__ X, const uint32_t* __restrict__ Wt,
                  const float* __restrict__ Bias, float* __restrict__ Out,
                  int M, int N, int K)
{
    __shared__ uint32_t Xp[2][64 * 16];
    __shared__ uint32_t Wp[2][64 * 16];

    const int tid  = threadIdx.x;
    const int lane = tid & 63;
    const int warp = tid >> 6;
    const int wm = warp >> 1, wn = warp & 1;
    const int m0 = blockIdx.y * TM;
    const int n0 = blockIdx.x * TN;
    const int cc = lane & 15;
    const int q  = lane >> 4;
    const int mi = cc >> 2;
    const int ni = cc & 3;
    const int xrd = (32 * wm + mi) * 16 + ((q ^ mi) << 2);
    int wrd[4];
    #pragma unroll
    for (int t = 0; t < 4; ++t)
        wrd[t] = (32 * wn + ni) * 16 + ((q ^ ni) << 2) + (((q + t) & 3) << 6);
    u16x8 bt[4];
    #pragma unroll
    for (int t = 0; t < 4; ++t) {
        unsigned short v = ((cc >> 2) == ((q + t) & 3)) ? (unsigned short)0x3F80
                                                        : (unsigned short)0;
        bt[t] = (u16x8){v, v, v, v, v, v, v, v};
    }
    const int srow = tid >> 2;
    const int soct = tid & 3;
    const uint32_t* xptr = X  + (size_t)(m0 + srow) * K + soct * 8;
    const uint32_t* wptr = Wt + (size_t)(n0 + srow) * K + soct * 8;
    const int st = srow * 16 + ((soct ^ (srow & 3)) << 2);

    f32x4 acc[8][2];
    #pragma unroll
    for (int a = 0; a < 8; ++a)
        #pragma unroll
        for (int bg = 0; bg < 2; ++bg) acc[a][bg] = (f32x4){0.f, 0.f, 0.f, 0.f};

    {
        uint4 a0 = *(const uint4*)(xptr), a1 = *(const uint4*)(xptr + 4);
        uint4 b0 = *(const uint4*)(wptr), b1 = *(const uint4*)(wptr + 4);
        *(uint4*)&Xp[0][st] = (uint4){pack_x(a0.x,a0.y), pack_x(a0.z,a0.w),
                                      pack_x(a1.x,a1.y), pack_x(a1.z,a1.w)};
        *(uint4*)&Wp[0][st] = (uint4){pack_w(b0.x,b0.y), pack_w(b0.z,b0.w),
                                      pack_w(b1.x,b1.y), pack_w(b1.z,b1.w)};
    }
    uint4 gx0 = {0,0,0,0}, gx1 = {0,0,0,0}, gw0 = {0,0,0,0}, gw1 = {0,0,0,0};
    const int ksteps = K / 32;
    if (ksteps > 1) {
        xptr += 32; wptr += 32;
        gx0 = *(const uint4*)(xptr); gx1 = *(const uint4*)(xptr + 4);
        gw0 = *(const uint4*)(wptr); gw1 = *(const uint4*)(wptr + 4);
    }
    __syncthreads();

    #pragma unroll 1
    for (int kt = 0; kt < ksteps; ++kt) {
        const int cur = kt & 1;
        if (kt + 1 < ksteps) {
            *(uint4*)&Xp[cur ^ 1][st] = (uint4){pack_x(gx0.x,gx0.y), pack_x(gx0.z,gx0.w),
                                                pack_x(gx1.x,gx1.y), pack_x(gx1.z,gx1.w)};
            *(uint4*)&Wp[cur ^ 1][st] = (uint4){pack_w(gw0.x,gw0.y), pack_w(gw0.z,gw0.w),
                                                pack_w(gw1.x,gw1.y), pack_w(gw1.z,gw1.w)};
            if (kt + 2 < ksteps) {
                xptr += 32; wptr += 32;
                gx0 = *(const uint4*)(xptr); gx1 = *(const uint4*)(xptr + 4);
                gw0 = *(const uint4*)(wptr); gw1 = *(const uint4*)(wptr + 4);
            }
        }
        u16x8 xf[8];
        #pragma unroll
        for (int a = 0; a < 8; ++a)
            xf[a] = __builtin_bit_cast(u16x8, *(const uint4*)&Xp[cur][xrd + a * 64]);
        #pragma unroll
        for (int bg = 0; bg < 2; ++bg) {
            u16x8 wf[4];
            #pragma unroll
            for (int t = 0; t < 4; ++t)
                wf[t] = __builtin_bit_cast(u16x8, *(const uint4*)&Wp[cur][wrd[t] + bg * 256]);
            #pragma unroll
            for (int t = 0; t < 4; ++t)
                #pragma unroll
                for (int a = 0; a < 8; ++a) {
                    u16x8 p = xf[a] + wf[t];
                    acc[a][bg] = __builtin_amdgcn_mfma_f32_16x16x32_bf16(
                        __builtin_bit_cast(s16x8, p),
                        __builtin_bit_cast(s16x8, bt[t]), acc[a][bg], 0, 0, 0);
                }
        }
        __syncthreads();
    }

    const int g = cc >> 2;
    f32x4 bias_[2];
    #pragma unroll
    for (int bg = 0; bg < 2; ++bg)
        bias_[bg] = *(const f32x4*)&Bias[n0 + 32 * wn + 16 * bg + 4 * g];
    #pragma unroll
    for (int a = 0; a < 8; ++a) {
        if ((cc & 3) == (a & 3)) {
            #pragma unroll
            for (int bg = 0; bg < 2; ++bg) {
                float o[4];
                #pragma unroll
                for (int j = 0; j < 4; ++j)
                    o[j] = bf16_to_f32(rnd_bf16(
                               bf16_to_f32(rnd_bf16(acc[a][bg][j])) + bias_[bg][j]));
                const size_t row = (size_t)(m0 + 32 * wm + 4 * a + q) * N;
                *(float4*)&Out[row + n0 + 32 * wn + 16 * bg + 4 * g] =
                    make_float4(o[0], o[1], o[2], o[3]);
            }
        }
    }
}

extern "C" void kernel_launch(void* const* d_in, const int* in_sizes, int n_in,
                              void* d_out, int out_size, void* d_ws, size_t ws_size,
                              hipStream_t stream) {
    (void)n_in; (void)out_size;
    const uint32_t* X = (const uint32_t*)d_in[0];   // f32 words (bf16-exact)
    const uint32_t* W = (const uint32_t*)d_in[1];
    const float*    B = (const float*)d_in[2];
    float* O = (float*)d_out;                       // f32 out (bf16-valued)

    int N = in_sizes[2];                       // bias [1,N], elements
    int K = (N > 0) ? in_sizes[1] / N : 0;     // weight [N,K]
    int M = (K > 0) ? in_sizes[0] / K : 0;     // input [M,K]
    if (N <= 0 || K <= 0 || M <= 0 ||
        (long long)N * K != (long long)in_sizes[1] ||
        (long long)M * K != (long long)in_sizes[0] ||
        (M % TM) || (N % TN) || (K % 64)) {
        M = 4096; K = 2048; N = 2048;          // documented problem shape
    }

    const size_t xq_words = (size_t)M * (K / 2);
    const size_t wq_words = (size_t)N * (K / 2);
    const size_t need = (xq_words + wq_words) * 4;

    dim3 grid(N / TN, M / TM);
    if (d_ws != nullptr && ws_size >= need) {
        uint32_t* Xq = (uint32_t*)d_ws;
        uint32_t* Wq = Xq + xq_words;
        pack_kernel<<<1024, 256, 0, stream>>>(X, Xq, (int)(xq_words / 2), 0);
        pack_kernel<<<1024, 256, 0, stream>>>(W, Wq, (int)(wq_words / 2), 1);
        fpma_gemm_pre<<<grid, 256, 0, stream>>>(Xq, Wq, B, O, M, N, K);
    } else {
        fpma_gemm_fb<<<grid, 256, 0, stream>>>(X, W, B, O, M, N, K);
    }
}

// Round 15
// 517.846 us; speedup vs baseline: 1.5649x; 1.0421x over previous
//
#include <hip/hip_runtime.h>
#include <stdint.h>

typedef unsigned short v2u   __attribute__((ext_vector_type(2)));
typedef unsigned short u16x8 __attribute__((ext_vector_type(8)));
typedef short          s16x8 __attribute__((ext_vector_type(8)));
typedef float          f32x4 __attribute__((ext_vector_type(4)));

#define TM 64
#define TN 64

__device__ __forceinline__ uint32_t rnd_bf16(float f) {
    uint32_t u = __builtin_bit_cast(uint32_t, f);
    return (u + 0x7FFFu + ((u >> 16) & 1u)) >> 16;   // RNE f32 -> bf16 (finite)
}
__device__ __forceinline__ float bf16_to_f32(uint32_t bits16) {
    return __builtin_bit_cast(float, bits16 << 16);
}

// HW-validated pack transforms (r12/r15): mag floored at 0x2000;
// X side folds (sign - 0x3F80), W side keeps sign|mag.
__device__ __forceinline__ uint32_t pack_x(uint32_t w0, uint32_t w1) {
    uint32_t u = (w0 >> 16) | (w1 & 0xFFFF0000u);
    const v2u vfloor = {0x2000, 0x2000};
    v2u m = __builtin_bit_cast(v2u, u & 0x7FFF7FFFu);
    m = __builtin_elementwise_max(m, vfloor);
    uint32_t c = (u & 0x80008000u) ^ 0xC080C080u;    // sign - 0x3F80
    v2u xp = m + __builtin_bit_cast(v2u, c);
    return __builtin_bit_cast(uint32_t, xp);
}
__device__ __forceinline__ uint32_t pack_w(uint32_t w0, uint32_t w1) {
    uint32_t v = (w0 >> 16) | (w1 & 0xFFFF0000u);
    const v2u vfloor = {0x2000, 0x2000};
    v2u m = __builtin_bit_cast(v2u, v & 0x7FFF7FFFu);
    m = __builtin_elementwise_max(m, vfloor);
    return __builtin_bit_cast(uint32_t, m) | (v & 0x80008000u);
}

// Fused pre-pack pass: X then W regions in one launch (grid-stride).
__global__ void pack_both(const uint32_t* __restrict__ X,
                          const uint32_t* __restrict__ W,
                          uint32_t* __restrict__ Xq,
                          uint32_t* __restrict__ Wq, int xn4, int wn4)
{
    int i = blockIdx.x * blockDim.x + threadIdx.x;
    const int stride = gridDim.x * blockDim.x;
    const int tot = xn4 + wn4;
    for (; i < tot; i += stride) {
        if (i < xn4) {
            uint4 v = ((const uint4*)X)[i];
            ((uint2*)Xq)[i] = (uint2){pack_x(v.x, v.y), pack_x(v.z, v.w)};
        } else {
            int j = i - xn4;
            uint4 v = ((const uint4*)W)[j];
            ((uint2*)Wq)[j] = (uint2){pack_w(v.x, v.y), pack_w(v.z, v.w)};
        }
    }
}

// ROUND 27. r26 (dot2 hybrid): 522 us REGRESSION — matrix work dropped as
// designed (MfmaUtil*wall=186us) but wall rose: in-wave filler work joins
// the critical path, doesn't fill gaps. Reverted. r23 accounting per SIMD:
// matrix 55%, VALU-issue 23%, ds ~5% — nothing saturated. Identified
// non-pipe losses: (a) grid tail: 2048 blocks / (256CU x 3 concurrent) =
// 2.67 rounds -> 3,3,2 slot imbalance ~ 50 us idle; (b) barrier skew ~16 us
// per halving (r23 measured). This round: BK=128 + LDS 64 KiB/block ->
// EXACTLY 2 blocks/CU -> 2048/(256x2) = 4.0 exact rounds (zero tail);
// barriers 32->16. DMA structure has no prefetch regs (no r18/r25 spill
// path). Pack launches fused (saves ~10 us). Accumulation order identical
// (k-ascending) -> bit-exact. If null/worse -> declare practical roofline
// (matrix floor 265 us / ~60% achievable duty, bracketed from 6 sides).
__global__ __launch_bounds__(256, 2)
void fpma_gemm_pre(const uint32_t* __restrict__ Xq,  // packed [M,K/2]
                   const uint32_t* __restrict__ Wq,  // packed [N,K/2]
                   const float*    __restrict__ Bias,// [N] f32 (bf16-exact)
                   float* __restrict__ Out,          // [M,N] f32 (bf16-valued)
                   int M, int N, int K)
{
    __shared__ uint32_t Xp[2][4][64 * 16];  // [buf][ksub][row*16], oct-swizzled
    __shared__ uint32_t Wp[2][4][64 * 16];

    const int tid  = threadIdx.x;
    const int lane = tid & 63;
    const int warp = tid >> 6;
    const int wm = warp >> 1, wn = warp & 1;
    const int m0 = blockIdx.y * TM;
    const int n0 = blockIdx.x * TN;

    // compute-side roles (r15/r16-validated A/D mapping)
    const int cc = lane & 15;
    const int q  = lane >> 4;            // k-octet within a 32-k sub-tile
    const int mi = cc >> 2;
    const int ni = cc & 3;

    const int xrd = (32 * wm + mi) * 16 + ((q ^ mi) << 2);
    int wrd[4];
    #pragma unroll
    for (int t = 0; t < 4; ++t)
        wrd[t] = (32 * wn + ni) * 16 + ((q ^ ni) << 2) + (((q + t) & 3) << 6);

    // B selectors: ones iff D col-group (cc>>2) == (q+t)&3
    u16x8 bt[4];
    #pragma unroll
    for (int t = 0; t < 4; ++t) {
        unsigned short v = ((cc >> 2) == ((q + t) & 3)) ? (unsigned short)0x3F80
                                                        : (unsigned short)0;
        bt[t] = (u16x8){v, v, v, v, v, v, v, v};
    }

    // staging roles: DMA dest linear tid*16B per sub-tile; swizzle moved to
    // the per-lane GLOBAL source octet (rule #21/m173; r22-validated).
    const int srow = tid >> 2;           // 0..63
    const int soct = tid & 3;            // 0..3
    const int Kp = K >> 1;               // packed words per row
    const int swz = (soct ^ (srow & 3)) << 2;
    const uint32_t* xsrc = Xq + (size_t)(m0 + srow) * Kp + swz;
    const uint32_t* wsrc = Wq + (size_t)(n0 + srow) * Kp + swz;

    f32x4 acc[8][2];
    #pragma unroll
    for (int a = 0; a < 8; ++a)
        #pragma unroll
        for (int bg = 0; bg < 2; ++bg) acc[a][bg] = (f32x4){0.f, 0.f, 0.f, 0.f};

    // prologue: DMA chunk 0 (four 32-k sub-tiles) into buf 0
    #pragma unroll
    for (int s = 0; s < 4; ++s) {
        __builtin_amdgcn_global_load_lds(xsrc + s * 16, &Xp[0][s][tid << 2], 16, 0, 0);
        __builtin_amdgcn_global_load_lds(wsrc + s * 16, &Wp[0][s][tid << 2], 16, 0, 0);
    }
    xsrc += 64; wsrc += 64;
    __syncthreads();   // drain: chunk-0 staging visible

    const int ksteps = K / 128;
    #pragma unroll 1
    for (int kt = 0; kt < ksteps; ++kt) {
        const int cur = kt & 1;
        if (kt + 1 < ksteps) {
            #pragma unroll
            for (int s = 0; s < 4; ++s) {
                __builtin_amdgcn_global_load_lds(xsrc + s * 16,
                    &Xp[cur ^ 1][s][tid << 2], 16, 0, 0);
                __builtin_amdgcn_global_load_lds(wsrc + s * 16,
                    &Wp[cur ^ 1][s][tid << 2], 16, 0, 0);
            }
            xsrc += 64; wsrc += 64;
        }

        __builtin_amdgcn_s_setprio(1);
        #pragma unroll
        for (int ks = 0; ks < 4; ++ks) {
            u16x8 xf[8];
            #pragma unroll
            for (int a = 0; a < 8; ++a)
                xf[a] = __builtin_bit_cast(u16x8,
                            *(const uint4*)&Xp[cur][ks][xrd + a * 64]);
            #pragma unroll
            for (int bg = 0; bg < 2; ++bg) {
                u16x8 wf[4];
                #pragma unroll
                for (int t = 0; t < 4; ++t)
                    wf[t] = __builtin_bit_cast(u16x8,
                                *(const uint4*)&Wp[cur][ks][wrd[t] + bg * 256]);
                #pragma unroll
                for (int t = 0; t < 4; ++t)
                    #pragma unroll
                    for (int a = 0; a < 8; ++a) {
                        u16x8 p = xf[a] + wf[t];       // 4x v_pk_add_u16
                        acc[a][bg] = __builtin_amdgcn_mfma_f32_16x16x32_bf16(
                            __builtin_bit_cast(s16x8, p),
                            __builtin_bit_cast(s16x8, bt[t]),
                            acc[a][bg], 0, 0, 0);
                    }
            }
        }
        __builtin_amdgcn_s_setprio(0);
        __syncthreads();   // drains DMA into cur^1 + lgkm; publishes
    }

    // Epilogue (r16-validated). acc[a][bg]: lane (cc,q), elem j =
    // out(m0+32wm+4a+q, n0+32wn+16bg+4*(cc>>2)+j); lane stores a's with
    // a&3 == cc&3 (disjoint, complete cover of 64x64 tile).
    const int g = cc >> 2;
    f32x4 bias_[2];
    #pragma unroll
    for (int bg = 0; bg < 2; ++bg)
        bias_[bg] = *(const f32x4*)&Bias[n0 + 32 * wn + 16 * bg + 4 * g];

    #pragma unroll
    for (int a = 0; a < 8; ++a) {
        if ((cc & 3) == (a & 3)) {
            #pragma unroll
            for (int bg = 0; bg < 2; ++bg) {
                float o[4];
                #pragma unroll
                for (int j = 0; j < 4; ++j)
                    o[j] = bf16_to_f32(rnd_bf16(
                               bf16_to_f32(rnd_bf16(acc[a][bg][j])) + bias_[bg][j]));
                const size_t row = (size_t)(m0 + 32 * wm + 4 * a + q) * N;
                *(float4*)&Out[row + n0 + 32 * wn + 16 * bg + 4 * g] =
                    make_float4(o[0], o[1], o[2], o[3]);
            }
        }
    }
}

// Fallback (ws too small): r16 path — in-kernel pack, BK=32, reg prefetch.
__global__ __launch_bounds__(256, 3)
void fpma_gemm_fb(const uint32_t* __restrict__ X, const uint32_t* __restrict__ Wt,
                  const float* __restrict__ Bias, float* __restrict__ Out,
                  int M, int N, int K)
{
    __shared__ uint32_t Xp[2][64 * 16];
    __shared__ uint32_t Wp[2][64 * 16];

    const int tid  = threadIdx.x;
    const int lane = tid & 63;
    const int warp = tid >> 6;
    const int wm = warp >> 1, wn = warp & 1;
    const int m0 = blockIdx.y * TM;
    const int n0 = blockIdx.x * TN;
    const int cc = lane & 15;
    const int q  = lane >> 4;
    const int mi = cc >> 2;
    const int ni = cc & 3;
    const int xrd = (32 * wm + mi) * 16 + ((q ^ mi) << 2);
    int wrd[4];
    #pragma unroll
    for (int t = 0; t < 4; ++t)
        wrd[t] = (32 * wn + ni) * 16 + ((q ^ ni) << 2) + (((q + t) & 3) << 6);
    u16x8 bt[4];
    #pragma unroll
    for (int t = 0; t < 4; ++t) {
        unsigned short v = ((cc >> 2) == ((q + t) & 3)) ? (unsigned short)0x3F80
                                                        : (unsigned short)0;
        bt[t] = (u16x8){v, v, v, v, v, v, v, v};
    }
    const int srow = tid >> 2;
    const int soct = tid & 3;
    const uint32_t* xptr = X  + (size_t)(m0 + srow) * K + soct * 8;
    const uint32_t* wptr = Wt + (size_t)(n0 + srow) * K + soct * 8;
    const int st = srow * 16 + ((soct ^ (srow & 3)) << 2);

    f32x4 acc[8][2];
    #pragma unroll
    for (int a = 0; a < 8; ++a)
        #pragma unroll
        for (int bg = 0; bg < 2; ++bg) acc[a][bg] = (f32x4){0.f, 0.f, 0.f, 0.f};

    {
        uint4 a0 = *(const uint4*)(xptr), a1 = *(const uint4*)(xptr + 4);
        uint4 b0 = *(const uint4*)(wptr), b1 = *(const uint4*)(wptr + 4);
        *(uint4*)&Xp[0][st] = (uint4){pack_x(a0.x,a0.y), pack_x(a0.z,a0.w),
                                      pack_x(a1.x,a1.y), pack_x(a1.z,a1.w)};
        *(uint4*)&Wp[0][st] = (uint4){pack_w(b0.x,b0.y), pack_w(b0.z,b0.w),
                                      pack_w(b1.x,b1.y), pack_w(b1.z,b1.w)};
    }
    uint4 gx0 = {0,0,0,0}, gx1 = {0,0,0,0}, gw0 = {0,0,0,0}, gw1 = {0,0,0,0};
    const int ksteps = K / 32;
    if (ksteps > 1) {
        xptr += 32; wptr += 32;
        gx0 = *(const uint4*)(xptr); gx1 = *(const uint4*)(xptr + 4);
        gw0 = *(const uint4*)(wptr); gw1 = *(const uint4*)(wptr + 4);
    }
    __syncthreads();

    #pragma unroll 1
    for (int kt = 0; kt < ksteps; ++kt) {
        const int cur = kt & 1;
        if (kt + 1 < ksteps) {
            *(uint4*)&Xp[cur ^ 1][st] = (uint4){pack_x(gx0.x,gx0.y), pack_x(gx0.z,gx0.w),
                                                pack_x(gx1.x,gx1.y), pack_x(gx1.z,gx1.w)};
            *(uint4*)&Wp[cur ^ 1][st] = (uint4){pack_w(gw0.x,gw0.y), pack_w(gw0.z,gw0.w),
                                                pack_w(gw1.x,gw1.y), pack_w(gw1.z,gw1.w)};
            if (kt + 2 < ksteps) {
                xptr += 32; wptr += 32;
                gx0 = *(const uint4*)(xptr); gx1 = *(const uint4*)(xptr + 4);
                gw0 = *(const uint4*)(wptr); gw1 = *(const uint4*)(wptr + 4);
            }
        }
        u16x8 xf[8];
        #pragma unroll
        for (int a = 0; a < 8; ++a)
            xf[a] = __builtin_bit_cast(u16x8, *(const uint4*)&Xp[cur][xrd + a * 64]);
        #pragma unroll
        for (int bg = 0; bg < 2; ++bg) {
            u16x8 wf[4];
            #pragma unroll
            for (int t = 0; t < 4; ++t)
                wf[t] = __builtin_bit_cast(u16x8, *(const uint4*)&Wp[cur][wrd[t] + bg * 256]);
            #pragma unroll
            for (int t = 0; t < 4; ++t)
                #pragma unroll
                for (int a = 0; a < 8; ++a) {
                    u16x8 p = xf[a] + wf[t];
                    acc[a][bg] = __builtin_amdgcn_mfma_f32_16x16x32_bf16(
                        __builtin_bit_cast(s16x8, p),
                        __builtin_bit_cast(s16x8, bt[t]), acc[a][bg], 0, 0, 0);
                }
        }
        __syncthreads();
    }

    const int g = cc >> 2;
    f32x4 bias_[2];
    #pragma unroll
    for (int bg = 0; bg < 2; ++bg)
        bias_[bg] = *(const f32x4*)&Bias[n0 + 32 * wn + 16 * bg + 4 * g];
    #pragma unroll
    for (int a = 0; a < 8; ++a) {
        if ((cc & 3) == (a & 3)) {
            #pragma unroll
            for (int bg = 0; bg < 2; ++bg) {
                float o[4];
                #pragma unroll
                for (int j = 0; j < 4; ++j)
                    o[j] = bf16_to_f32(rnd_bf16(
                               bf16_to_f32(rnd_bf16(acc[a][bg][j])) + bias_[bg][j]));
                const size_t row = (size_t)(m0 + 32 * wm + 4 * a + q) * N;
                *(float4*)&Out[row + n0 + 32 * wn + 16 * bg + 4 * g] =
                    make_float4(o[0], o[1], o[2], o[3]);
            }
        }
    }
}

extern "C" void kernel_launch(void* const* d_in, const int* in_sizes, int n_in,
                              void* d_out, int out_size, void* d_ws, size_t ws_size,
                              hipStream_t stream) {
    (void)n_in; (void)out_size;
    const uint32_t* X = (const uint32_t*)d_in[0];   // f32 words (bf16-exact)
    const uint32_t* W = (const uint32_t*)d_in[1];
    const float*    B = (const float*)d_in[2];
    float* O = (float*)d_out;                       // f32 out (bf16-valued)

    int N = in_sizes[2];                       // bias [1,N], elements
    int K = (N > 0) ? in_sizes[1] / N : 0;     // weight [N,K]
    int M = (K > 0) ? in_sizes[0] / K : 0;     // input [M,K]
    if (N <= 0 || K <= 0 || M <= 0 ||
        (long long)N * K != (long long)in_sizes[1] ||
        (long long)M * K != (long long)in_sizes[0] ||
        (M % TM) || (N % TN) || (K % 32)) {
        M = 4096; K = 2048; N = 2048;          // documented problem shape
    }

    const size_t xq_words = (size_t)M * (K / 2);
    const size_t wq_words = (size_t)N * (K / 2);
    const size_t need = (xq_words + wq_words) * 4;

    dim3 grid(N / TN, M / TM);
    if (d_ws != nullptr && ws_size >= need && (K % 128) == 0) {
        uint32_t* Xq = (uint32_t*)d_ws;
        uint32_t* Wq = Xq + xq_words;
        pack_both<<<2048, 256, 0, stream>>>(X, W, Xq, Wq,
                                            (int)(xq_words / 2), (int)(wq_words / 2));
        fpma_gemm_pre<<<grid, 256, 0, stream>>>(Xq, Wq, B, O, M, N, K);
    } else {
        fpma_gemm_fb<<<grid, 256, 0, stream>>>(X, W, B, O, M, N, K);
    }
}